// Round 1
// baseline (566.778 us; speedup 1.0000x reference)
//
#include <hip/hip_runtime.h>

// H2G2: 2-layer RGCN (R=4, per-relation mean) + mean-pool + linear.
// R1->R2: atomic scatter -> CSR gather. R2->R3: atomic pool -> segmented pool+cls.
// R3->R4: fp32 LDS GEMM -> bf16 MFMA. R4->R5: CSR via 2-level bucket sort.
// R5->R7: aggregate-then-transform; K=320 MFMA GEMM. R8 FAILED: Y-in-LDS fusion
//   capped occupancy (28%). R9: separate agg (8 gathers in flight) = 240us.
// R10: register-resident fusion (231us): lane (m,quad) owns the 64 Y channels
//   its MFMA A-frag needs; zero LDS. Layer counters: Occ 23%, VALU 15%,
//   MfmaUtil 1.5%, HBM 16% -> latency-bound, wave-starved (3128 waves total),
//   ~16 serial dependent loads/lane (4 relation segments x unroll-2).
// R11: (a) merge the 4 relation loops into ONE edge loop using the et bits
//   already in eidx, one-hot predicated FMA accumulate -> single loop,
//   unroll x4 = 8 row loads in flight, chain ~16 -> ~4 latencies;
//   (b) split each node's edges across a wave PAIR (parity), f32 partial
//   exchange via 32KB rotated-float4 LDS (conflict-free), ws=0 combines +
//   MFMA. 32 nodes/block -> 6252 waves (2x supply). launch_bounds(256,4)
//   caps VGPR<=128 -> 4 blocks/CU.

#define RR 4
#define HH 64
#define KK 320         // (RR+1)*HH
#define LWN (HH * KK)  // weights per layer = 20480
#define EPB 4096       // edges per binning block
#define SBUF_D 6144    // per-bucket staging cap

using frag_ab = __attribute__((ext_vector_type(8))) short;
using frag_cd = __attribute__((ext_vector_type(4))) float;

__device__ inline short f2bf(float f) {
    unsigned u = __builtin_bit_cast(unsigned, f);
    unsigned r = u + 0x7fffu + ((u >> 16) & 1u);  // RNE
    return (short)(r >> 16);
}
__device__ inline float bf2f(short s) {
    unsigned u = ((unsigned)(unsigned short)s) << 16;
    return __builtin_bit_cast(float, u);
}

// ---- prep: fused init-independent work, partitioned by blockIdx ----
__global__ __launch_bounds__(256) void prep_kernel(
    const int* __restrict__ dst, int E, int NBUCK, int* __restrict__ bcnt,
    const float* __restrict__ basis1, const float* __restrict__ comp1, const float* __restrict__ root1,
    const float* __restrict__ basis2, const float* __restrict__ comp2, const float* __restrict__ root2,
    short* __restrict__ W1t, short* __restrict__ W2t,
    const int* __restrict__ batch, int* __restrict__ gstart, int N, int G,
    int* __restrict__ row_ptr,
    const float* __restrict__ x, short* __restrict__ Xb,
    int ebl, int wbl, int nb) {
    const int bid = blockIdx.x;
    const int t = threadIdx.x;
    if (bid < ebl) {  // ---- histogram of dst>>8 ----
        __shared__ int lc[256];
        lc[t] = 0;
        __syncthreads();
        int e0 = bid * EPB, e1 = min(e0 + EPB, E);
        for (int e = e0 + t; e < e1; e += 256) atomicAdd(&lc[dst[e] >> 8], 1);
        __syncthreads();
        if (t < NBUCK && lc[t]) atomicAdd(&bcnt[t], lc[t]);
    } else if (bid < ebl + wbl) {  // ---- weights: Wt[c*320+k] = Wstack[k][c] ----
        int w = (bid - ebl) * 256 + t;
        int layer = w / LWN;
        int rem = w - layer * LWN;
        int c = rem / KK;
        int k = rem - c * KK;
        const float* basis = layer ? basis2 : basis1;
        const float* comp  = layer ? comp2  : comp1;
        const float* root  = layer ? root2  : root1;
        short* Wt          = layer ? W2t    : W1t;
        float v;
        if (k < HH) {
            v = root[k * HH + c];
        } else {
            int r = (k >> 6) - 1, kk = k & 63;
            v = 0.f;
#pragma unroll
            for (int b = 0; b < RR; ++b) v += comp[r * RR + b] * basis[(b * HH + kk) * HH + c];
        }
        Wt[c * KK + k] = f2bf(v);
    } else if (bid < ebl + wbl + nb) {  // ---- gstart + row_ptr sentinel ----
        int i = (bid - ebl - wbl) * 256 + t;
        if (i == 0) row_ptr[N] = E;
        if (i < N) {
            int b1 = batch[i];
            int b0 = (i == 0) ? -1 : batch[i - 1];
            for (int g = b0 + 1; g <= b1; ++g) gstart[g] = i;
            if (i == N - 1)
                for (int g = b1 + 1; g <= G; ++g) gstart[g] = N;
        }
    } else {  // ---- convert x fp32 -> bf16 ----
        int i4 = (bid - ebl - wbl - nb) * 256 + t;
        int base = i4 * 4;
        if (base < N * 64) {
            float4 f = *(const float4*)&x[base];
            short4 s;
            s.x = f2bf(f.x); s.y = f2bf(f.y); s.z = f2bf(f.z); s.w = f2bf(f.w);
            *(short4*)&Xb[base] = s;
        }
    }
}

// ---- bin: block-local counting sort by bucket; packed payload src:16|et:2|dl:8 ----
__global__ __launch_bounds__(256) void bin_kernel(const int* __restrict__ src,
                                                  const int* __restrict__ dst,
                                                  const int* __restrict__ et,
                                                  const int* __restrict__ bcnt,
                                                  int* __restrict__ cur0,
                                                  int* __restrict__ tmp, int E) {
    __shared__ int lc[256];
    __shared__ int lscan[257];
    __shared__ int lbase[256];
    __shared__ int ss[256];
    __shared__ int sbuf[EPB];
    int t = threadIdx.x;
    int bv = bcnt[t];
    ss[t] = bv;
    __syncthreads();
#pragma unroll
    for (int off = 1; off < 256; off <<= 1) {
        int u = (t >= off) ? ss[t - off] : 0;
        __syncthreads();
        ss[t] += u;
        __syncthreads();
    }
    int boff_t = ss[t] - bv;
    lc[t] = 0;
    __syncthreads();
    int e0 = blockIdx.x * EPB;
    int e1 = min(e0 + EPB, E);
    for (int e = e0 + t; e < e1; e += 256) atomicAdd(&lc[dst[e] >> 8], 1);
    __syncthreads();
    int v = lc[t];
    ss[t] = v;
    __syncthreads();
#pragma unroll
    for (int off = 1; off < 256; off <<= 1) {
        int u = (t >= off) ? ss[t - off] : 0;
        __syncthreads();
        ss[t] += u;
        __syncthreads();
    }
    lscan[t] = ss[t] - v;
    if (t == 255) lscan[256] = ss[255];
    if (v) lbase[t] = boff_t + atomicAdd(&cur0[t], v);
    lc[t] = 0;
    __syncthreads();
    for (int e = e0 + t; e < e1; e += 256) {
        int d = dst[e];
        int b = d >> 8;
        int p = (src[e] << 10) | (et[e] << 8) | (d & 255);
        int pos = lscan[b] + atomicAdd(&lc[b], 1);
        sbuf[pos] = p;
    }
    __syncthreads();
    int tot = lscan[256];
    for (int i = t; i < tot; i += 256) {
        int lo = 0, hi = 255;
        while (lo < hi) { int mid = (lo + hi + 1) >> 1; if (lscan[mid] <= i) lo = mid; else hi = mid - 1; }
        tmp[lbase[lo] + (i - lscan[lo])] = sbuf[i];
    }
}

// ---- csr: per-bucket finalize: row_ptr, rp4 (per-rel starts), inv,
//      eidx sorted by (dst, rel) ----
__global__ __launch_bounds__(256) void csr_kernel(const int* __restrict__ tmp,
                                                  const int* __restrict__ bcnt,
                                                  int* __restrict__ row_ptr,
                                                  int4* __restrict__ rp4,
                                                  int* __restrict__ eidx,
                                                  float* __restrict__ inv, int N) {
    __shared__ int cnt4l[1024];  // counts -> in-place per-(dl,r) start offsets/cursors
    __shared__ int dscan[256];
    __shared__ int ss[256];
    __shared__ int sb[SBUF_D];
    int b = blockIdx.x, t = threadIdx.x;
    int bv = bcnt[t];
    ss[t] = bv;
    __syncthreads();
#pragma unroll
    for (int off = 1; off < 256; off <<= 1) {
        int u = (t >= off) ? ss[t - off] : 0;
        __syncthreads();
        ss[t] += u;
        __syncthreads();
    }
    __shared__ int s0s, s1s;
    if (t == b) { s0s = ss[t] - bv; s1s = ss[t]; }
    __syncthreads();
    int s0 = s0s, s1 = s1s;
    int len = s1 - s0;
    for (int i = t; i < 1024; i += 256) cnt4l[i] = 0;
    __syncthreads();
    for (int i = s0 + t; i < s1; i += 256) {
        int e = tmp[i];
        atomicAdd(&cnt4l[((e & 255) << 2) | ((e >> 8) & 3)], 1);
    }
    __syncthreads();
    int c0 = cnt4l[t * 4], c1 = cnt4l[t * 4 + 1], c2 = cnt4l[t * 4 + 2], c3 = cnt4l[t * 4 + 3];
    int deg = c0 + c1 + c2 + c3;
    ss[t] = deg;
    __syncthreads();
#pragma unroll
    for (int off = 1; off < 256; off <<= 1) {
        int u = (t >= off) ? ss[t - off] : 0;
        __syncthreads();
        ss[t] += u;
        __syncthreads();
    }
    dscan[t] = ss[t] - deg;
    int d0 = b << 8;
    int d = d0 + t;
    // inv from raw counts
    if (d < N) {
        inv[d * 4 + 0] = 1.0f / fmaxf((float)c0, 1.0f);
        inv[d * 4 + 1] = 1.0f / fmaxf((float)c1, 1.0f);
        inv[d * 4 + 2] = 1.0f / fmaxf((float)c2, 1.0f);
        inv[d * 4 + 3] = 1.0f / fmaxf((float)c3, 1.0f);
    }
    // in-place convert cnt4l to per-(dl,r) start offsets (bucket-relative)
    int base = dscan[t];
    cnt4l[t * 4] = base;
    cnt4l[t * 4 + 1] = base + c0;
    cnt4l[t * 4 + 2] = base + c0 + c1;
    cnt4l[t * 4 + 3] = base + c0 + c1 + c2;
    if (d < N) {
        row_ptr[d] = s0 + base;
        rp4[d] = make_int4(s0 + base, s0 + base + c0, s0 + base + c0 + c1,
                           s0 + base + c0 + c1 + c2);
    }
    __syncthreads();
    if (len <= SBUF_D) {
        for (int i = s0 + t; i < s1; i += 256) {
            int e = tmp[i];
            int key = ((e & 255) << 2) | ((e >> 8) & 3);
            int pos = atomicAdd(&cnt4l[key], 1);  // cursor on start offsets
            sb[pos] = ((e >> 10) << 2) | ((e >> 8) & 3);  // (src<<2)|et
        }
        __syncthreads();
        for (int i = t; i < len; i += 256) eidx[s0 + i] = sb[i];
    } else {
        for (int i = s0 + t; i < s1; i += 256) {
            int e = tmp[i];
            int key = ((e & 255) << 2) | ((e >> 8) & 3);
            int pos = atomicAdd(&cnt4l[key], 1);
            eidx[s0 + pos] = ((e >> 10) << 2) | ((e >> 8) & 3);
        }
    }
}

// ---- fused layer (R11): 32 nodes/block, wave pair splits edges by parity.
// Merged single edge loop (relation from eidx low bits, one-hot predicated
// FMA accumulate), unroll x4 for MLP. Partials exchanged via rotated-float4
// LDS (32KB/block, conflict-free); ws=0 combines, MFMAs, stores. ----
__global__ __launch_bounds__(256, 4) void layer_kernel(
    const int* __restrict__ row_ptr,
    const int* __restrict__ eidx,
    const short* __restrict__ Xb,
    const float* __restrict__ inv,
    const short* __restrict__ Wt,
    const float* __restrict__ bias,
    short* __restrict__ out, int n) {
    __shared__ float xbuf[2][64][64];  // [pair][lane][64 partial floats]
    const int t = threadIdx.x;
    const int wv = t >> 6;
    const int pair = wv >> 1;   // which 16-node group
    const int ws = wv & 1;      // edge-parity half
    const int l = t & 63;
    const int m = l & 15;
    const int quad = l >> 4;
    const int node = blockIdx.x * 32 + pair * 16 + m;
    const bool valid = node < n;

    float accL[4][8], accH[4][8];
#pragma unroll
    for (int r = 0; r < 4; ++r)
#pragma unroll
        for (int j = 0; j < 8; ++j) { accL[r][j] = 0.f; accH[r][j] = 0.f; }

    int k0 = 0, k1 = 0;
    float4 iv = make_float4(0.f, 0.f, 0.f, 0.f);
    if (valid) {
        k0 = row_ptr[node];
        k1 = row_ptr[node + 1];
        iv = *(const float4*)&inv[node * 4];
    }
    const short* xbq = Xb + quad * 8;

#define ACC(P, XL, XH)                                                        \
    {                                                                         \
        int r_ = (P) & 3;                                                     \
        float s0_ = (r_ == 0) ? 1.f : 0.f;                                    \
        float s1_ = (r_ == 1) ? 1.f : 0.f;                                    \
        float s2_ = (r_ == 2) ? 1.f : 0.f;                                    \
        float s3_ = (r_ == 3) ? 1.f : 0.f;                                    \
        _Pragma("unroll") for (int j = 0; j < 8; ++j) {                       \
            float vl = bf2f((XL)[j]);                                         \
            float vh = bf2f((XH)[j]);                                         \
            accL[0][j] += vl * s0_; accH[0][j] += vh * s0_;                   \
            accL[1][j] += vl * s1_; accH[1][j] += vh * s1_;                   \
            accL[2][j] += vl * s2_; accH[2][j] += vh * s2_;                   \
            accL[3][j] += vl * s3_; accH[3][j] += vh * s3_;                   \
        }                                                                     \
    }

    int k = k0 + ws;  // parity split across the wave pair
    for (; k + 6 < k1; k += 8) {  // 4 edges, 8 row loads in flight
        int p0 = eidx[k];
        int p1 = eidx[k + 2];
        int p2 = eidx[k + 4];
        int p3 = eidx[k + 6];
        const short* a0p = xbq + (size_t)(p0 >> 2) * 64;
        const short* a1p = xbq + (size_t)(p1 >> 2) * 64;
        const short* a2p = xbq + (size_t)(p2 >> 2) * 64;
        const short* a3p = xbq + (size_t)(p3 >> 2) * 64;
        frag_ab x0l = *(const frag_ab*)a0p;
        frag_ab x0h = *(const frag_ab*)(a0p + 32);
        frag_ab x1l = *(const frag_ab*)a1p;
        frag_ab x1h = *(const frag_ab*)(a1p + 32);
        frag_ab x2l = *(const frag_ab*)a2p;
        frag_ab x2h = *(const frag_ab*)(a2p + 32);
        frag_ab x3l = *(const frag_ab*)a3p;
        frag_ab x3h = *(const frag_ab*)(a3p + 32);
        ACC(p0, x0l, x0h)
        ACC(p1, x1l, x1h)
        ACC(p2, x2l, x2h)
        ACC(p3, x3l, x3h)
    }
    for (; k < k1; k += 2) {  // remainder (<=3 edges)
        int p0 = eidx[k];
        const short* a0p = xbq + (size_t)(p0 >> 2) * 64;
        frag_ab x0l = *(const frag_ab*)a0p;
        frag_ab x0h = *(const frag_ab*)(a0p + 32);
        ACC(p0, x0l, x0h)
    }
#undef ACC

    // ---- exchange: ws=1 writes partials, ws=0 combines. Rotated float4:
    // lane l's slot q lives at (q+l)&15 -> every inst spreads over all banks.
    if (ws == 1) {
        float4* row = (float4*)xbuf[pair][l];
#pragma unroll
        for (int q = 0; q < 8; ++q) {
            int rr = q >> 1, o = (q & 1) * 4;
            row[(q + l) & 15] =
                make_float4(accL[rr][o], accL[rr][o + 1], accL[rr][o + 2], accL[rr][o + 3]);
            row[(q + 8 + l) & 15] =
                make_float4(accH[rr][o], accH[rr][o + 1], accH[rr][o + 2], accH[rr][o + 3]);
        }
    }
    __syncthreads();
    if (ws == 1) return;  // gather half done; MFMA handled by ws=0
    {
        const float4* row = (const float4*)xbuf[pair][l];
#pragma unroll
        for (int q = 0; q < 8; ++q) {
            int rr = q >> 1, o = (q & 1) * 4;
            float4 vL = row[(q + l) & 15];
            float4 vH = row[(q + 8 + l) & 15];
            accL[rr][o] += vL.x; accL[rr][o + 1] += vL.y;
            accL[rr][o + 2] += vL.z; accL[rr][o + 3] += vL.w;
            accH[rr][o] += vH.x; accH[rr][o + 1] += vH.y;
            accH[rr][o + 2] += vH.z; accH[rr][o + 3] += vH.w;
        }
    }

    // build A-frags: a[0..1] = X row; a[2+2r], a[3+2r] = Y (scaled, bf16)
    frag_ab a[10];
#pragma unroll
    for (int f = 0; f < 10; ++f) a[f] = frag_ab{};
    if (valid) {
        const short* xr = Xb + (size_t)node * 64 + quad * 8;
        a[0] = *(const frag_ab*)xr;
        a[1] = *(const frag_ab*)(xr + 32);
    }
    {
        float s0 = iv.x, s1 = iv.y, s2 = iv.z, s3 = iv.w;
#pragma unroll
        for (int j = 0; j < 8; ++j) {
            a[2][j] = f2bf(accL[0][j] * s0); a[3][j] = f2bf(accH[0][j] * s0);
            a[4][j] = f2bf(accL[1][j] * s1); a[5][j] = f2bf(accH[1][j] * s1);
            a[6][j] = f2bf(accL[2][j] * s2); a[7][j] = f2bf(accH[2][j] * s2);
            a[8][j] = f2bf(accL[3][j] * s3); a[9][j] = f2bf(accH[3][j] * s3);
        }
    }

    const int nrow_base = blockIdx.x * 32 + pair * 16 + quad * 4;
#pragma unroll
    for (int ct = 0; ct < 4; ++ct) {
        const short* bp = Wt + (size_t)(ct * 16 + m) * KK + quad * 8;
        frag_cd acc = {0.f, 0.f, 0.f, 0.f};
#pragma unroll
        for (int f = 0; f < 10; ++f) {
            frag_ab bf = *(const frag_ab*)(bp + f * 32);
            acc = __builtin_amdgcn_mfma_f32_16x16x32_bf16(a[f], bf, acc, 0, 0, 0);
        }
        int col = ct * 16 + m;
        float bv = bias[col];
#pragma unroll
        for (int r = 0; r < 4; ++r) {
            int nr = nrow_base + r;
            if (nr < n) out[(size_t)nr * 64 + col] = f2bf(fmaxf(acc[r] + bv, 0.f));
        }
    }
}

// ---- pool (segmented) + classifier ----
__global__ __launch_bounds__(256) void pool_cls_kernel(const short* __restrict__ h2,
                                                       const int* __restrict__ gstart,
                                                       const float* __restrict__ w,
                                                       const float* __restrict__ b,
                                                       float* __restrict__ out) {
    __shared__ float red[4][64];
    const int g = blockIdx.x;
    const int t = threadIdx.x;
    const int h = t & 63;
    const int wv = t >> 6;
    const int s = gstart[g], e = gstart[g + 1];

    float acc = 0.f;
    for (int i = s + wv; i < e; i += 4) acc += bf2f(h2[(size_t)i * 64 + h]);
    red[wv][h] = acc;
    __syncthreads();
    if (wv == 0) {
        float sum = red[0][h] + red[1][h] + red[2][h] + red[3][h];
        red[0][h] = sum / fmaxf((float)(e - s), 1.0f);
    }
    __syncthreads();
    if (t < 4) {
        float sres = 0.f;
#pragma unroll 8
        for (int hh = 0; hh < 64; ++hh) sres += red[0][hh] * w[hh * 4 + t];
        out[g * 4 + t] = sres + b[t];
    }
}

extern "C" void kernel_launch(void* const* d_in, const int* in_sizes, int n_in,
                              void* d_out, int out_size, void* d_ws, size_t ws_size,
                              hipStream_t stream) {
    const float* x        = (const float*)d_in[0];
    const int* edge_index = (const int*)d_in[1];
    const int* edge_type  = (const int*)d_in[2];
    const int* batch      = (const int*)d_in[3];
    const float* basis1 = (const float*)d_in[4];
    const float* comp1  = (const float*)d_in[5];
    const float* root1  = (const float*)d_in[6];
    const float* bias1  = (const float*)d_in[7];
    const float* basis2 = (const float*)d_in[8];
    const float* comp2  = (const float*)d_in[9];
    const float* root2  = (const float*)d_in[10];
    const float* bias2  = (const float*)d_in[11];
    const float* clas_w = (const float*)d_in[12];
    const float* clas_b = (const float*)d_in[13];

    const int N = in_sizes[0] / 64;
    const int E = in_sizes[2];
    const int G = out_size / 4;
    const int* src = edge_index;
    const int* dst = edge_index + E;
    const int NBUCK = (N + 255) >> 8;

    char* base = (char*)d_ws;
    size_t off = 0;
    auto carve = [&](size_t bytes) { void* p = base + off; off = (off + bytes + 15) & ~(size_t)15; return p; };
    int*   bcnt    = (int*)carve(sizeof(int) * 256);
    int*   cur0    = (int*)carve(sizeof(int) * 256);
    int*   row_ptr = (int*)carve(sizeof(int) * ((size_t)N + 1));
    int4*  rp4     = (int4*)carve(sizeof(int4) * (size_t)N);
    int*   gstart  = (int*)carve(sizeof(int) * ((size_t)G + 1));
    int*   eidx    = (int*)carve(sizeof(int) * (size_t)E);
    int*   tmp     = (int*)carve(sizeof(int) * (size_t)E);
    float* inv     = (float*)carve(sizeof(float) * (size_t)N * RR);
    short* W1t     = (short*)carve(sizeof(short) * LWN);
    short* W2t     = (short*)carve(sizeof(short) * LWN);
    short* Xb1     = (short*)carve(sizeof(short) * (size_t)N * 64);
    short* H1      = (short*)carve(sizeof(short) * (size_t)N * 64);
    short* H2      = (short*)carve(sizeof(short) * (size_t)N * 64);

    const int nb  = (N + 255) / 256;
    const int ebl = (E + EPB - 1) / EPB;
    const int wbl = (2 * LWN + 255) / 256;
    const int cvb = (N * 64 / 4 + 255) / 256;
    const int prep_blocks = ebl + wbl + nb + cvb;

    hipMemsetAsync(bcnt, 0, sizeof(int) * 512, stream);  // bcnt + cur0

    prep_kernel<<<prep_blocks, 256, 0, stream>>>(
        dst, E, NBUCK, bcnt,
        basis1, comp1, root1, basis2, comp2, root2, W1t, W2t,
        batch, gstart, N, G, row_ptr, x, Xb1, ebl, wbl, nb);
    bin_kernel<<<ebl, 256, 0, stream>>>(src, dst, edge_type, bcnt, cur0, tmp, E);
    csr_kernel<<<NBUCK, 256, 0, stream>>>(tmp, bcnt, row_ptr, rp4, eidx, inv, N);

    const int layer_blocks = (N + 31) / 32;

    layer_kernel<<<layer_blocks, 256, 0, stream>>>(row_ptr, eidx, Xb1, inv, W1t, bias1, H1, N);
    layer_kernel<<<layer_blocks, 256, 0, stream>>>(row_ptr, eidx, H1, inv, W2t, bias2, H2, N);

    pool_cls_kernel<<<G, 256, 0, stream>>>(H2, gstart, clas_w, clas_b, (float*)d_out);
}

// Round 2
// 229.593 us; speedup vs baseline: 2.4686x; 2.4686x over previous
//
#include <hip/hip_runtime.h>

// H2G2: 2-layer RGCN (R=4, per-relation mean) + mean-pool + linear.
// R1->R2: atomic scatter -> CSR gather. R2->R3: atomic pool -> segmented pool+cls.
// R3->R4: fp32 LDS GEMM -> bf16 MFMA. R4->R5: CSR via 2-level bucket sort.
// R5->R7: aggregate-then-transform; K=320 MFMA GEMM. R8 FAILED: Y-in-LDS fusion
//   capped occupancy. R9: separate agg = 240us. R10: register-resident fusion
//   (231us, layer 47us): latency-bound, wave-starved, ~16 serial loads/lane.
// R11 FAILED (567us): merged one-hot loop + edge-parity wave pair, BUT
//   __launch_bounds__(256,4) capped unified VGPR+AGPR at 128 -> 64 acc floats
//   + 8 frags spilled to SCRATCH: WRITE_SIZE 6MB->432MB, layer 221us.
//   Lesson: R10's 64 fp32 accs lived in spare AGPRs; never cap min-waves here.
// R12: keep merged one-hot loop (relation bits already in eidx; single loop,
//   4 edges in flight) but split CHANNELS (not edges) across the wave pair:
//   ws=0 gathers low 8ch of quad, ws=1 high 8ch -> acc = 32 floats/lane,
//   16 frag VGPRs in flight; ws=1 scales+packs bf16 A-frags into 8KB LDS,
//   ws=0 consumes directly in MFMA. Plain launch_bounds(256) -> AGPR headroom,
//   no scratch. 32 nodes/block -> 6252 waves (2x R10 supply).

#define RR 4
#define HH 64
#define KK 320         // (RR+1)*HH
#define LWN (HH * KK)  // weights per layer = 20480
#define EPB 4096       // edges per binning block
#define SBUF_D 6144    // per-bucket staging cap

using frag_ab = __attribute__((ext_vector_type(8))) short;
using frag_cd = __attribute__((ext_vector_type(4))) float;

__device__ inline short f2bf(float f) {
    unsigned u = __builtin_bit_cast(unsigned, f);
    unsigned r = u + 0x7fffu + ((u >> 16) & 1u);  // RNE
    return (short)(r >> 16);
}
__device__ inline float bf2f(short s) {
    unsigned u = ((unsigned)(unsigned short)s) << 16;
    return __builtin_bit_cast(float, u);
}

// ---- prep: fused init-independent work, partitioned by blockIdx ----
__global__ __launch_bounds__(256) void prep_kernel(
    const int* __restrict__ dst, int E, int NBUCK, int* __restrict__ bcnt,
    const float* __restrict__ basis1, const float* __restrict__ comp1, const float* __restrict__ root1,
    const float* __restrict__ basis2, const float* __restrict__ comp2, const float* __restrict__ root2,
    short* __restrict__ W1t, short* __restrict__ W2t,
    const int* __restrict__ batch, int* __restrict__ gstart, int N, int G,
    int* __restrict__ row_ptr,
    const float* __restrict__ x, short* __restrict__ Xb,
    int ebl, int wbl, int nb) {
    const int bid = blockIdx.x;
    const int t = threadIdx.x;
    if (bid < ebl) {  // ---- histogram of dst>>8 ----
        __shared__ int lc[256];
        lc[t] = 0;
        __syncthreads();
        int e0 = bid * EPB, e1 = min(e0 + EPB, E);
        for (int e = e0 + t; e < e1; e += 256) atomicAdd(&lc[dst[e] >> 8], 1);
        __syncthreads();
        if (t < NBUCK && lc[t]) atomicAdd(&bcnt[t], lc[t]);
    } else if (bid < ebl + wbl) {  // ---- weights: Wt[c*320+k] = Wstack[k][c] ----
        int w = (bid - ebl) * 256 + t;
        int layer = w / LWN;
        int rem = w - layer * LWN;
        int c = rem / KK;
        int k = rem - c * KK;
        const float* basis = layer ? basis2 : basis1;
        const float* comp  = layer ? comp2  : comp1;
        const float* root  = layer ? root2  : root1;
        short* Wt          = layer ? W2t    : W1t;
        float v;
        if (k < HH) {
            v = root[k * HH + c];
        } else {
            int r = (k >> 6) - 1, kk = k & 63;
            v = 0.f;
#pragma unroll
            for (int b = 0; b < RR; ++b) v += comp[r * RR + b] * basis[(b * HH + kk) * HH + c];
        }
        Wt[c * KK + k] = f2bf(v);
    } else if (bid < ebl + wbl + nb) {  // ---- gstart + row_ptr sentinel ----
        int i = (bid - ebl - wbl) * 256 + t;
        if (i == 0) row_ptr[N] = E;
        if (i < N) {
            int b1 = batch[i];
            int b0 = (i == 0) ? -1 : batch[i - 1];
            for (int g = b0 + 1; g <= b1; ++g) gstart[g] = i;
            if (i == N - 1)
                for (int g = b1 + 1; g <= G; ++g) gstart[g] = N;
        }
    } else {  // ---- convert x fp32 -> bf16 ----
        int i4 = (bid - ebl - wbl - nb) * 256 + t;
        int base = i4 * 4;
        if (base < N * 64) {
            float4 f = *(const float4*)&x[base];
            short4 s;
            s.x = f2bf(f.x); s.y = f2bf(f.y); s.z = f2bf(f.z); s.w = f2bf(f.w);
            *(short4*)&Xb[base] = s;
        }
    }
}

// ---- bin: block-local counting sort by bucket; packed payload src:16|et:2|dl:8 ----
__global__ __launch_bounds__(256) void bin_kernel(const int* __restrict__ src,
                                                  const int* __restrict__ dst,
                                                  const int* __restrict__ et,
                                                  const int* __restrict__ bcnt,
                                                  int* __restrict__ cur0,
                                                  int* __restrict__ tmp, int E) {
    __shared__ int lc[256];
    __shared__ int lscan[257];
    __shared__ int lbase[256];
    __shared__ int ss[256];
    __shared__ int sbuf[EPB];
    int t = threadIdx.x;
    int bv = bcnt[t];
    ss[t] = bv;
    __syncthreads();
#pragma unroll
    for (int off = 1; off < 256; off <<= 1) {
        int u = (t >= off) ? ss[t - off] : 0;
        __syncthreads();
        ss[t] += u;
        __syncthreads();
    }
    int boff_t = ss[t] - bv;
    lc[t] = 0;
    __syncthreads();
    int e0 = blockIdx.x * EPB;
    int e1 = min(e0 + EPB, E);
    for (int e = e0 + t; e < e1; e += 256) atomicAdd(&lc[dst[e] >> 8], 1);
    __syncthreads();
    int v = lc[t];
    ss[t] = v;
    __syncthreads();
#pragma unroll
    for (int off = 1; off < 256; off <<= 1) {
        int u = (t >= off) ? ss[t - off] : 0;
        __syncthreads();
        ss[t] += u;
        __syncthreads();
    }
    lscan[t] = ss[t] - v;
    if (t == 255) lscan[256] = ss[255];
    if (v) lbase[t] = boff_t + atomicAdd(&cur0[t], v);
    lc[t] = 0;
    __syncthreads();
    for (int e = e0 + t; e < e1; e += 256) {
        int d = dst[e];
        int b = d >> 8;
        int p = (src[e] << 10) | (et[e] << 8) | (d & 255);
        int pos = lscan[b] + atomicAdd(&lc[b], 1);
        sbuf[pos] = p;
    }
    __syncthreads();
    int tot = lscan[256];
    for (int i = t; i < tot; i += 256) {
        int lo = 0, hi = 255;
        while (lo < hi) { int mid = (lo + hi + 1) >> 1; if (lscan[mid] <= i) lo = mid; else hi = mid - 1; }
        tmp[lbase[lo] + (i - lscan[lo])] = sbuf[i];
    }
}

// ---- csr: per-bucket finalize: row_ptr, rp4 (per-rel starts), inv,
//      eidx sorted by (dst, rel) ----
__global__ __launch_bounds__(256) void csr_kernel(const int* __restrict__ tmp,
                                                  const int* __restrict__ bcnt,
                                                  int* __restrict__ row_ptr,
                                                  int4* __restrict__ rp4,
                                                  int* __restrict__ eidx,
                                                  float* __restrict__ inv, int N) {
    __shared__ int cnt4l[1024];  // counts -> in-place per-(dl,r) start offsets/cursors
    __shared__ int dscan[256];
    __shared__ int ss[256];
    __shared__ int sb[SBUF_D];
    int b = blockIdx.x, t = threadIdx.x;
    int bv = bcnt[t];
    ss[t] = bv;
    __syncthreads();
#pragma unroll
    for (int off = 1; off < 256; off <<= 1) {
        int u = (t >= off) ? ss[t - off] : 0;
        __syncthreads();
        ss[t] += u;
        __syncthreads();
    }
    __shared__ int s0s, s1s;
    if (t == b) { s0s = ss[t] - bv; s1s = ss[t]; }
    __syncthreads();
    int s0 = s0s, s1 = s1s;
    int len = s1 - s0;
    for (int i = t; i < 1024; i += 256) cnt4l[i] = 0;
    __syncthreads();
    for (int i = s0 + t; i < s1; i += 256) {
        int e = tmp[i];
        atomicAdd(&cnt4l[((e & 255) << 2) | ((e >> 8) & 3)], 1);
    }
    __syncthreads();
    int c0 = cnt4l[t * 4], c1 = cnt4l[t * 4 + 1], c2 = cnt4l[t * 4 + 2], c3 = cnt4l[t * 4 + 3];
    int deg = c0 + c1 + c2 + c3;
    ss[t] = deg;
    __syncthreads();
#pragma unroll
    for (int off = 1; off < 256; off <<= 1) {
        int u = (t >= off) ? ss[t - off] : 0;
        __syncthreads();
        ss[t] += u;
        __syncthreads();
    }
    dscan[t] = ss[t] - deg;
    int d0 = b << 8;
    int d = d0 + t;
    // inv from raw counts
    if (d < N) {
        inv[d * 4 + 0] = 1.0f / fmaxf((float)c0, 1.0f);
        inv[d * 4 + 1] = 1.0f / fmaxf((float)c1, 1.0f);
        inv[d * 4 + 2] = 1.0f / fmaxf((float)c2, 1.0f);
        inv[d * 4 + 3] = 1.0f / fmaxf((float)c3, 1.0f);
    }
    // in-place convert cnt4l to per-(dl,r) start offsets (bucket-relative)
    int base = dscan[t];
    cnt4l[t * 4] = base;
    cnt4l[t * 4 + 1] = base + c0;
    cnt4l[t * 4 + 2] = base + c0 + c1;
    cnt4l[t * 4 + 3] = base + c0 + c1 + c2;
    if (d < N) {
        row_ptr[d] = s0 + base;
        rp4[d] = make_int4(s0 + base, s0 + base + c0, s0 + base + c0 + c1,
                           s0 + base + c0 + c1 + c2);
    }
    __syncthreads();
    if (len <= SBUF_D) {
        for (int i = s0 + t; i < s1; i += 256) {
            int e = tmp[i];
            int key = ((e & 255) << 2) | ((e >> 8) & 3);
            int pos = atomicAdd(&cnt4l[key], 1);  // cursor on start offsets
            sb[pos] = ((e >> 10) << 2) | ((e >> 8) & 3);  // (src<<2)|et
        }
        __syncthreads();
        for (int i = t; i < len; i += 256) eidx[s0 + i] = sb[i];
    } else {
        for (int i = s0 + t; i < s1; i += 256) {
            int e = tmp[i];
            int key = ((e & 255) << 2) | ((e >> 8) & 3);
            int pos = atomicAdd(&cnt4l[key], 1);
            eidx[s0 + pos] = ((e >> 10) << 2) | ((e >> 8) & 3);
        }
    }
}

// ---- fused layer (R12): 32 nodes/block; wave pair splits CHANNELS.
// ws=0 gathers low 8ch of its quad, ws=1 the high 8ch; both walk the full
// edge list (merged, one-hot accumulate, 4 edges in flight). ws=1 scales to
// bf16 and drops its 4 A-frags in 8KB LDS; ws=0 packs its own + LDS frags
// and runs the K=320 MFMA. acc = 32 floats/lane; no scratch possible. ----
__global__ __launch_bounds__(256) void layer_kernel(
    const int* __restrict__ row_ptr,
    const int* __restrict__ eidx,
    const short* __restrict__ Xb,
    const float* __restrict__ inv,
    const short* __restrict__ Wt,
    const float* __restrict__ bias,
    short* __restrict__ out, int n) {
    __shared__ short xpack[2][64][32];  // [pair][lane][4 frags x 8 bf16] = 8KB
    const int t = threadIdx.x;
    const int wv = t >> 6;
    const int pair = wv >> 1;   // which 16-node group
    const int ws = wv & 1;      // channel half: 0 = quad*8, 1 = 32+quad*8
    const int l = t & 63;
    const int m = l & 15;
    const int quad = l >> 4;
    const int node = blockIdx.x * 32 + pair * 16 + m;
    const bool valid = node < n;

    float acc[4][8];  // [rel][8 ch of this lane's half]
#pragma unroll
    for (int r = 0; r < 4; ++r)
#pragma unroll
        for (int j = 0; j < 8; ++j) acc[r][j] = 0.f;

    int k0 = 0, k1 = 0;
    float4 iv = make_float4(0.f, 0.f, 0.f, 0.f);
    if (valid) {
        k0 = row_ptr[node];
        k1 = row_ptr[node + 1];
        iv = *(const float4*)&inv[node * 4];
    }
    const short* xbq = Xb + ws * 32 + quad * 8;

#define ACC(P, F)                                                             \
    {                                                                         \
        int r_ = (P) & 3;                                                     \
        float s0_ = (r_ == 0) ? 1.f : 0.f;                                    \
        float s1_ = (r_ == 1) ? 1.f : 0.f;                                    \
        float s2_ = (r_ == 2) ? 1.f : 0.f;                                    \
        float s3_ = (r_ == 3) ? 1.f : 0.f;                                    \
        _Pragma("unroll") for (int j = 0; j < 8; ++j) {                       \
            float v_ = bf2f((F)[j]);                                          \
            acc[0][j] += v_ * s0_;                                            \
            acc[1][j] += v_ * s1_;                                            \
            acc[2][j] += v_ * s2_;                                            \
            acc[3][j] += v_ * s3_;                                            \
        }                                                                     \
    }

    int k = k0;
    for (; k + 3 < k1; k += 4) {  // 4 edges in flight
        int p0 = eidx[k];
        int p1 = eidx[k + 1];
        int p2 = eidx[k + 2];
        int p3 = eidx[k + 3];
        const short* a0p = xbq + (size_t)(p0 >> 2) * 64;
        const short* a1p = xbq + (size_t)(p1 >> 2) * 64;
        const short* a2p = xbq + (size_t)(p2 >> 2) * 64;
        const short* a3p = xbq + (size_t)(p3 >> 2) * 64;
        frag_ab f0 = *(const frag_ab*)a0p;
        frag_ab f1 = *(const frag_ab*)a1p;
        frag_ab f2 = *(const frag_ab*)a2p;
        frag_ab f3 = *(const frag_ab*)a3p;
        ACC(p0, f0)
        ACC(p1, f1)
        ACC(p2, f2)
        ACC(p3, f3)
    }
    for (; k < k1; ++k) {  // remainder (<=3 edges)
        int p0 = eidx[k];
        const short* a0p = xbq + (size_t)(p0 >> 2) * 64;
        frag_ab f0 = *(const frag_ab*)a0p;
        ACC(p0, f0)
    }
#undef ACC

    // scale by per-relation inv-degree, pack to bf16 A-frag halves
    frag_ab y[4];
    {
        float s0 = iv.x, s1 = iv.y, s2 = iv.z, s3 = iv.w;
#pragma unroll
        for (int j = 0; j < 8; ++j) {
            y[0][j] = f2bf(acc[0][j] * s0);
            y[1][j] = f2bf(acc[1][j] * s1);
            y[2][j] = f2bf(acc[2][j] * s2);
            y[3][j] = f2bf(acc[3][j] * s3);
        }
    }

    // exchange: ws=1 deposits its 4 high-half frags; ws=0 consumes.
    if (ws == 1) {
#pragma unroll
        for (int r = 0; r < 4; ++r)
            *(frag_ab*)&xpack[pair][l][r * 8] = y[r];
    }
    __syncthreads();
    if (ws == 1) return;

    // build A-frags: a[0..1] = X row; a[2+2r] = own (low), a[3+2r] = LDS (high)
    frag_ab a[10];
    a[0] = frag_ab{};
    a[1] = frag_ab{};
    if (valid) {
        const short* xr = Xb + (size_t)node * 64 + quad * 8;
        a[0] = *(const frag_ab*)xr;
        a[1] = *(const frag_ab*)(xr + 32);
    }
#pragma unroll
    for (int r = 0; r < 4; ++r) {
        a[2 + 2 * r] = y[r];
        a[3 + 2 * r] = *(const frag_ab*)&xpack[pair][l][r * 8];
    }

    const int nrow_base = blockIdx.x * 32 + pair * 16 + quad * 4;
#pragma unroll
    for (int ct = 0; ct < 4; ++ct) {
        const short* bp = Wt + (size_t)(ct * 16 + m) * KK + quad * 8;
        frag_cd c = {0.f, 0.f, 0.f, 0.f};
#pragma unroll
        for (int f = 0; f < 10; ++f) {
            frag_ab bf = *(const frag_ab*)(bp + f * 32);
            c = __builtin_amdgcn_mfma_f32_16x16x32_bf16(a[f], bf, c, 0, 0, 0);
        }
        int col = ct * 16 + m;
        float bv = bias[col];
#pragma unroll
        for (int r = 0; r < 4; ++r) {
            int nr = nrow_base + r;
            if (nr < n) out[(size_t)nr * 64 + col] = f2bf(fmaxf(c[r] + bv, 0.f));
        }
    }
}

// ---- pool (segmented) + classifier ----
__global__ __launch_bounds__(256) void pool_cls_kernel(const short* __restrict__ h2,
                                                       const int* __restrict__ gstart,
                                                       const float* __restrict__ w,
                                                       const float* __restrict__ b,
                                                       float* __restrict__ out) {
    __shared__ float red[4][64];
    const int g = blockIdx.x;
    const int t = threadIdx.x;
    const int h = t & 63;
    const int wv = t >> 6;
    const int s = gstart[g], e = gstart[g + 1];

    float acc = 0.f;
    for (int i = s + wv; i < e; i += 4) acc += bf2f(h2[(size_t)i * 64 + h]);
    red[wv][h] = acc;
    __syncthreads();
    if (wv == 0) {
        float sum = red[0][h] + red[1][h] + red[2][h] + red[3][h];
        red[0][h] = sum / fmaxf((float)(e - s), 1.0f);
    }
    __syncthreads();
    if (t < 4) {
        float sres = 0.f;
#pragma unroll 8
        for (int hh = 0; hh < 64; ++hh) sres += red[0][hh] * w[hh * 4 + t];
        out[g * 4 + t] = sres + b[t];
    }
}

extern "C" void kernel_launch(void* const* d_in, const int* in_sizes, int n_in,
                              void* d_out, int out_size, void* d_ws, size_t ws_size,
                              hipStream_t stream) {
    const float* x        = (const float*)d_in[0];
    const int* edge_index = (const int*)d_in[1];
    const int* edge_type  = (const int*)d_in[2];
    const int* batch      = (const int*)d_in[3];
    const float* basis1 = (const float*)d_in[4];
    const float* comp1  = (const float*)d_in[5];
    const float* root1  = (const float*)d_in[6];
    const float* bias1  = (const float*)d_in[7];
    const float* basis2 = (const float*)d_in[8];
    const float* comp2  = (const float*)d_in[9];
    const float* root2  = (const float*)d_in[10];
    const float* bias2  = (const float*)d_in[11];
    const float* clas_w = (const float*)d_in[12];
    const float* clas_b = (const float*)d_in[13];

    const int N = in_sizes[0] / 64;
    const int E = in_sizes[2];
    const int G = out_size / 4;
    const int* src = edge_index;
    const int* dst = edge_index + E;
    const int NBUCK = (N + 255) >> 8;

    char* base = (char*)d_ws;
    size_t off = 0;
    auto carve = [&](size_t bytes) { void* p = base + off; off = (off + bytes + 15) & ~(size_t)15; return p; };
    int*   bcnt    = (int*)carve(sizeof(int) * 256);
    int*   cur0    = (int*)carve(sizeof(int) * 256);
    int*   row_ptr = (int*)carve(sizeof(int) * ((size_t)N + 1));
    int4*  rp4     = (int4*)carve(sizeof(int4) * (size_t)N);
    int*   gstart  = (int*)carve(sizeof(int) * ((size_t)G + 1));
    int*   eidx    = (int*)carve(sizeof(int) * (size_t)E);
    int*   tmp     = (int*)carve(sizeof(int) * (size_t)E);
    float* inv     = (float*)carve(sizeof(float) * (size_t)N * RR);
    short* W1t     = (short*)carve(sizeof(short) * LWN);
    short* W2t     = (short*)carve(sizeof(short) * LWN);
    short* Xb1     = (short*)carve(sizeof(short) * (size_t)N * 64);
    short* H1      = (short*)carve(sizeof(short) * (size_t)N * 64);
    short* H2      = (short*)carve(sizeof(short) * (size_t)N * 64);

    const int nb  = (N + 255) / 256;
    const int ebl = (E + EPB - 1) / EPB;
    const int wbl = (2 * LWN + 255) / 256;
    const int cvb = (N * 64 / 4 + 255) / 256;
    const int prep_blocks = ebl + wbl + nb + cvb;

    hipMemsetAsync(bcnt, 0, sizeof(int) * 512, stream);  // bcnt + cur0

    prep_kernel<<<prep_blocks, 256, 0, stream>>>(
        dst, E, NBUCK, bcnt,
        basis1, comp1, root1, basis2, comp2, root2, W1t, W2t,
        batch, gstart, N, G, row_ptr, x, Xb1, ebl, wbl, nb);
    bin_kernel<<<ebl, 256, 0, stream>>>(src, dst, edge_type, bcnt, cur0, tmp, E);
    csr_kernel<<<NBUCK, 256, 0, stream>>>(tmp, bcnt, row_ptr, rp4, eidx, inv, N);

    const int layer_blocks = (N + 31) / 32;

    layer_kernel<<<layer_blocks, 256, 0, stream>>>(row_ptr, eidx, Xb1, inv, W1t, bias1, H1, N);
    layer_kernel<<<layer_blocks, 256, 0, stream>>>(row_ptr, eidx, H1, inv, W2t, bias2, H2, N);

    pool_cls_kernel<<<G, 256, 0, stream>>>(H2, gstart, clas_w, clas_b, (float*)d_out);
}